// Round 13
// baseline (63.965 us; speedup 1.0000x reference)
//
#include <hip/hip_runtime.h>
#include <math.h>

// Canny NMS mask, bit-exact vs the validated round-5 pipeline.
// v8 = v5 structure (58.5us best) with f64-in-LDS staging:
//   - s_gray, s_blur stored as double: the f32->f64 cvt happens ONCE per
//     staged value instead of 25x (blur) + 9x (sobel) per consuming pixel.
//   - all arithmetic chains verbatim; operand VALUES bit-identical
//     ((double)f32 == stored widened f32; blur stores (double)(float)acc).
//   - LDS 24.7KB -> 6 blocks/CU, launch_bounds(256,6) (VGPR cap 85).
// Border tiles: same pipeline, masked (v5-verbatim logic, f64 LDS).

#define NT 256

__device__ __forceinline__ float grayf(float r, float g, float b) {
  return __fadd_rn(__fadd_rn(__fmul_rn(0.299f, r), __fmul_rn(0.587f, g)),
                   __fmul_rn(0.114f, b));
}

// sector: f32 slope test w/ guard band; in-band -> verbatim atan2f chain
__device__ __forceinline__ int sectorf(float gxf, float gyf) {
  const float Tnf = 0.41421356237309504880f;
  const float BETAf = 1e-4f;
  const float RAD2DEG = (float)(180.0 / 3.14159265358979323846);
  float uf = (gyf < 0.0f) ? -gxf : gxf;
  float vf = fabsf(gyf);
  float au = fabsf(uf);
  float p = au * Tnf, qq = vf * Tnf;
  int sec;
  if (uf > 0.0f)      sec = (vf < p) ? 0 : (uf > qq) ? 1 : 2;
  else if (uf < 0.0f) sec = (uf > -qq) ? 2 : (vf > p) ? 3 : 0;
  else                sec = (vf > 0.0f) ? 2 : 0;
  bool slow = (fabsf(vf - p) <= p * BETAf) || (fabsf(au - qq) <= qq * BETAf);
  if (slow) {
    float ang = __fmul_rn(atan2f(gyf, gxf), RAD2DEG);
    if (ang < 0.0f) ang = __fadd_rn(ang, 180.0f);
    sec = (ang < 22.5f) ? 0 : (ang < 67.5f) ? 1
        : (ang < 112.5f) ? 2 : (ang < 157.5f) ? 3 : 0;
  }
  return sec;
}

template <bool BORDER>
__device__ __forceinline__ void canny_tile(
    const float* __restrict__ base, float* __restrict__ outp,
    int bx0, int by0, double* s_gray, double* s_blur, float* s_mag,
    unsigned char* s_sec, const double* w64, int tid) {
  const size_t plane = (size_t)512 * 512;

  // ---- Phase 1: gray 24x72 -> LDS as double ----
  if (BORDER) {
    for (int i = tid; i < 24 * 72; i += NT) {
      int ly = i / 72, lx = i - ly * 72;
      int gy = by0 - 4 + ly, gx = bx0 - 4 + lx;
      float val = 0.0f;
      if (gy >= 0 && gy < 512 && gx >= 0 && gx < 512) {
        size_t idx = (size_t)gy * 512 + gx;
        val = grayf(base[idx], base[idx + plane], base[idx + 2 * plane]);
      }
      s_gray[i] = (double)val;
    }
  } else {
    for (int t = tid; t < 24 * 18; t += NT) {
      int row = t / 18, c4 = (t - row * 18) * 4;
      size_t idx = (size_t)(by0 - 4 + row) * 512 + (bx0 - 4 + c4);
      float4 r = *(const float4*)(base + idx);
      float4 g = *(const float4*)(base + idx + plane);
      float4 b = *(const float4*)(base + idx + 2 * plane);
      double2 lo, hi;
      lo.x = (double)grayf(r.x, g.x, b.x);
      lo.y = (double)grayf(r.y, g.y, b.y);
      hi.x = (double)grayf(r.z, g.z, b.z);
      hi.y = (double)grayf(r.w, g.w, b.w);
      *(double2*)(s_gray + row * 72 + c4) = lo;
      *(double2*)(s_gray + row * 72 + c4 + 2) = hi;
    }
  }
  __syncthreads();

  // ---- Phase 2: blur 20x68, vertical sliding 5x5 f64 window, fma chain ----
  auto blur_run = [&](int col, int q) {
    const int y0 = q * 5;
    const int ix = bx0 - 2 + col;
    const bool colok = !BORDER || (ix >= 0 && ix < 512);
    double win[5][5];
#pragma unroll
    for (int r = 0; r < 4; ++r)
#pragma unroll
      for (int c = 0; c < 5; ++c)
        win[r][c] = s_gray[(y0 + r) * 72 + col + c];
#pragma unroll
    for (int y = 0; y < 5; ++y) {
      const int pin = (y + 4) % 5;
#pragma unroll
      for (int c = 0; c < 5; ++c)
        win[pin][c] = s_gray[(y0 + y + 4) * 72 + col + c];
      double acc = 0.0;
#pragma unroll
      for (int r = 0; r < 5; ++r) {
        const int ph = (y + r) % 5;
#pragma unroll
        for (int c = 0; c < 5; ++c)
          acc = __builtin_fma(w64[r * 5 + c], win[ph][c], acc);
      }
      if (BORDER) {
        int iy = by0 - 2 + y0 + y;
        s_blur[(y0 + y) * 68 + col] =
            (colok && iy >= 0 && iy < 512) ? (double)(float)acc : 0.0;
      } else {
        s_blur[(y0 + y) * 68 + col] = (double)(float)acc;
      }
    }
  };
  blur_run(tid & 63, tid >> 6);
  if (tid < 16) blur_run(64 + (tid & 3), tid >> 2);
  __syncthreads();

  // ---- Phase 3: sobel + mag + sector (18x66), vertical sliding 3x3 ----
  auto sob_run = [&](int col, int q) {
    const int y0  = (q < 2) ? q * 5 : 10 + (q - 2) * 4;
    const int len = (q < 2) ? 5 : 4;
    const int ix = bx0 - 1 + col;
    const bool colok = !BORDER || (ix >= 0 && ix < 512);
    double wn[3][3];
#pragma unroll
    for (int r = 0; r < 2; ++r)
#pragma unroll
      for (int c = 0; c < 3; ++c)
        wn[r][c] = s_blur[(y0 + r) * 68 + col + c];
#pragma unroll
    for (int y = 0; y < 5; ++y) {
      if (y < len) {
        const int pin = (y + 2) % 3;
#pragma unroll
        for (int c = 0; c < 3; ++c)
          wn[pin][c] = s_blur[(y0 + y + 2) * 68 + col + c];
        const int r0 = y % 3, r1 = (y + 1) % 3, r2 = (y + 2) % 3;
        double b00 = wn[r0][0], b01 = wn[r0][1], b02 = wn[r0][2];
        double b10 = wn[r1][0],                  b12 = wn[r1][2];
        double b20 = wn[r2][0], b21 = wn[r2][1], b22 = wn[r2][2];
        float gxf = (float)(((b02 - b00) + 2.0 * (b12 - b10)) + (b22 - b20));
        float gyf = (float)(((b20 - b00) + 2.0 * (b21 - b01)) + (b22 - b02));

        float mval;
        if (BORDER) {
          int iy = by0 - 1 + y0 + y;
          mval = 0.0f;
          if (colok && iy >= 0 && iy < 512)
            mval = __fsqrt_rn(__fadd_rn(__fmul_rn(gxf, gxf), __fmul_rn(gyf, gyf)));
        } else {
          mval = __fsqrt_rn(__fadd_rn(__fmul_rn(gxf, gxf), __fmul_rn(gyf, gyf)));
        }
        s_mag[(y0 + y) * 66 + col] = mval;
        s_sec[(y0 + y) * 66 + col] = (unsigned char)sectorf(gxf, gyf);
      }
    }
  };
  sob_run(tid & 63, tid >> 6);
  if (tid < 8) sob_run(64 + (tid & 1), tid >> 1);
  __syncthreads();

  // ---- Phase 4: NMS (16x64), vertical sliding 3x3 mag window ----
  {
    const int col = tid & 63, q = tid >> 6;
    const int y0 = q * 4;
    float mw[3][3];
#pragma unroll
    for (int r = 0; r < 2; ++r)
#pragma unroll
      for (int c = 0; c < 3; ++c)
        mw[r][c] = s_mag[(y0 + r) * 66 + col + c];
#pragma unroll
    for (int y = 0; y < 4; ++y) {
      const int pin = (y + 2) % 3;
#pragma unroll
      for (int c = 0; c < 3; ++c)
        mw[pin][c] = s_mag[(y0 + y + 2) * 66 + col + c];
      const int r0 = y % 3, r1 = (y + 1) % 3, r2 = (y + 2) % 3;
      int sec = s_sec[(y0 + y + 1) * 66 + (col + 1)];
      float m = mw[r1][1];
      bool z;
      if (sec == 0)      z = (m >= mw[r1][0]) && (m >= mw[r1][2]);
      else if (sec == 1) z = (m >= mw[r2][0]) && (m >= mw[r0][2]);
      else if (sec == 2) z = (m >= mw[r0][1]) && (m >= mw[r2][1]);
      else               z = (m >= mw[r0][0]) && (m >= mw[r2][2]);
      outp[(size_t)(by0 + y0 + y) * 512 + (bx0 + col)] = z ? 0.998f : 0.002f;
    }
  }
}

__global__ __launch_bounds__(NT, 6) void canny_v8(const float* __restrict__ x,
                                                  float* __restrict__ out) {
  __shared__ __align__(16) double s_gray[24 * 72];  // 13824 B
  __shared__ __align__(16) double s_blur[20 * 68];  // 10880 B (tot 24704 B)
  // P3/P4 overlay into the gray region (gray dead after P2):
  float* s_mag = (float*)s_gray;                    // 18*66 f32 = 4752 B
  unsigned char* s_sec = (unsigned char*)(s_mag + 1188);  // + 1188 B

  const int tid = threadIdx.x;
  const int bid = blockIdx.x;
  const int txi = bid & 7, tyi = (bid >> 3) & 31;
  const int bx0 = txi * 64;
  const int by0 = tyi * 16;
  const int n   = bid >> 8;
  const float* base = x + (size_t)n * 3 * 512 * 512;
  float* outp = out + (size_t)n * 512 * 512;

  // weights: CR f32 exps, numpy-pairwise f32 sum, f32 divide (verbatim;
  // constant-folds at compile time)
  const float E05 = (float)exp(-0.5);
  const float E1  = (float)exp(-1.0);
  const float E2  = (float)exp(-2.0);
  const float E25 = (float)exp(-2.5);
  const float E4  = (float)exp(-4.0);
  const float a25[25] = {E4,E25,E2,E25,E4,  E25,E1,E05,E1,E25,
                         E2,E05,1.0f,E05,E2, E25,E1,E05,E1,E25,
                         E4,E25,E2,E25,E4};
  float r8[8];
#pragma unroll
  for (int j = 0; j < 8; ++j)
    r8[j] = __fadd_rn(__fadd_rn(a25[j], a25[j + 8]), a25[j + 16]);
  float S32 = __fadd_rn(__fadd_rn(__fadd_rn(r8[0], r8[1]), __fadd_rn(r8[2], r8[3])),
                        __fadd_rn(__fadd_rn(r8[4], r8[5]), __fadd_rn(r8[6], r8[7])));
  S32 = __fadd_rn(S32, a25[24]);
  double w64[25];
#pragma unroll
  for (int t = 0; t < 25; ++t) w64[t] = (double)__fdiv_rn(a25[t], S32);

  const bool border = (txi == 0) | (txi == 7) | (tyi == 0) | (tyi == 31);
  if (border)
    canny_tile<true>(base, outp, bx0, by0, s_gray, s_blur, s_mag, s_sec, w64, tid);
  else
    canny_tile<false>(base, outp, bx0, by0, s_gray, s_blur, s_mag, s_sec, w64, tid);
}

extern "C" void kernel_launch(void* const* d_in, const int* in_sizes, int n_in,
                              void* d_out, int out_size, void* d_ws, size_t ws_size,
                              hipStream_t stream) {
  const float* x = (const float*)d_in[0];
  float* out = (float*)d_out;
  hipLaunchKernelGGL(canny_v8, dim3(8192), dim3(NT), 0, stream, x, out);
}